// Round 3
// baseline (360.823 us; speedup 1.0000x reference)
//
#include <hip/hip_runtime.h>
#include <math.h>

// Problem constants (from reference)
#define B_ROWS 65536
#define C_COLS 1024
#define GRID_BLOCKS 2048
#define BLOCK_THREADS 256
#define WAVES_PER_BLOCK (BLOCK_THREADS / 64)
#define TOTAL_WAVES (GRID_BLOCKS * WAVES_PER_BLOCK)

__device__ __forceinline__ float softplus(float x) {
    // log1p(exp(x)), numerically stable for large |x|
    float ax = fabsf(x);
    return fmaxf(x, 0.0f) + log1pf(expf(-ax));
}

__global__ __launch_bounds__(BLOCK_THREADS) void rank_loss_partial(
        const float* __restrict__ scores,
        const int* __restrict__ labels,
        double* __restrict__ partials) {
    const int waveId = threadIdx.x >> 6;
    const int lane = threadIdx.x & 63;
    const int globalWave = blockIdx.x * WAVES_PER_BLOCK + waveId;

    const float MARGIN_POS = 2.5f;
    const float MARGIN_NEG = 0.5f;
    const float GAMMA = 2.0f;

    double acc = 0.0;
    // B_ROWS / TOTAL_WAVES == 8 exactly; process 2 rows per iteration for ILP.
    for (int base = globalWave; base < B_ROWS; base += 2 * TOTAL_WAVES) {
        const int rowA = base;
        const int rowB = base + TOTAL_WAVES;  // always < B_ROWS (exact division)
        const int labA = labels[rowA];        // wave-uniform -> scalar load
        const int labB = labels[rowB];
        // Direct gather of the positive score: wave-uniform address -> s_load.
        const float sposA = scores[(size_t)rowA * C_COLS + labA];
        const float sposB = scores[(size_t)rowB * C_COLS + labB];
        const float4* __restrict__ rpA = (const float4*)(scores + (size_t)rowA * C_COLS);
        const float4* __restrict__ rpB = (const float4*)(scores + (size_t)rowB * C_COLS);

        float mA = -INFINITY, mB = -INFINITY;
        #pragma unroll
        for (int it = 0; it < 4; ++it) {
            const int c4 = it * 64 + lane;  // coalesced float4 index within row
            float4 va = rpA[c4];
            float4 vb = rpB[c4];
            const int b0 = c4 << 2;
            // Mask out the positive column from the negative-max.
            const float a0 = (b0     == labA) ? -INFINITY : va.x;
            const float a1 = (b0 + 1 == labA) ? -INFINITY : va.y;
            const float a2 = (b0 + 2 == labA) ? -INFINITY : va.z;
            const float a3 = (b0 + 3 == labA) ? -INFINITY : va.w;
            const float b0v = (b0     == labB) ? -INFINITY : vb.x;
            const float b1v = (b0 + 1 == labB) ? -INFINITY : vb.y;
            const float b2v = (b0 + 2 == labB) ? -INFINITY : vb.z;
            const float b3v = (b0 + 3 == labB) ? -INFINITY : vb.w;
            mA = fmaxf(mA, fmaxf(fmaxf(a0, a1), fmaxf(a2, a3)));
            mB = fmaxf(mB, fmaxf(fmaxf(b0v, b1v), fmaxf(b2v, b3v)));
        }

        // wave-level max reduce (64 lanes) — two rows interleaved
        #pragma unroll
        for (int off = 32; off > 0; off >>= 1) {
            mA = fmaxf(mA, __shfl_down(mA, off, 64));
            mB = fmaxf(mB, __shfl_down(mB, off, 64));
        }

        if (lane == 0) {
            const float snA = (labA == 0) ? 0.0f : mA;
            const float snB = (labB == 0) ? 0.0f : mB;
            acc += (double)(softplus(GAMMA * (MARGIN_POS - sposA)) +
                            softplus(GAMMA * (MARGIN_NEG + snA)));
            acc += (double)(softplus(GAMMA * (MARGIN_POS - sposB)) +
                            softplus(GAMMA * (MARGIN_NEG + snB)));
        }
    }

    // block reduction of per-wave accumulators (only lane 0 of each wave holds data)
    __shared__ double sacc[WAVES_PER_BLOCK];
    if (lane == 0) sacc[waveId] = acc;
    __syncthreads();
    if (threadIdx.x == 0) {
        double s = 0.0;
        #pragma unroll
        for (int i = 0; i < WAVES_PER_BLOCK; ++i) s += sacc[i];
        partials[blockIdx.x] = s;
    }
}

__global__ __launch_bounds__(256) void rank_loss_final(
        const double* __restrict__ partials, float* __restrict__ out) {
    __shared__ double sdata[256];
    double s = 0.0;
    for (int i = threadIdx.x; i < GRID_BLOCKS; i += 256) s += partials[i];
    sdata[threadIdx.x] = s;
    __syncthreads();
    #pragma unroll
    for (int off = 128; off > 0; off >>= 1) {
        if (threadIdx.x < off) sdata[threadIdx.x] += sdata[threadIdx.x + off];
        __syncthreads();
    }
    if (threadIdx.x == 0) out[0] = (float)(sdata[0] / (double)B_ROWS);
}

extern "C" void kernel_launch(void* const* d_in, const int* in_sizes, int n_in,
                              void* d_out, int out_size, void* d_ws, size_t ws_size,
                              hipStream_t stream) {
    const float* scores = (const float*)d_in[0];
    const int* labels = (const int*)d_in[1];
    float* out = (float*)d_out;
    double* partials = (double*)d_ws;  // GRID_BLOCKS doubles = 16 KB

    rank_loss_partial<<<GRID_BLOCKS, BLOCK_THREADS, 0, stream>>>(scores, labels, partials);
    rank_loss_final<<<1, 256, 0, stream>>>(partials, out);
}